// Round 1
// baseline (95.903 us; speedup 1.0000x reference)
//
#include <hip/hip_runtime.h>

// SigNet forward: time-augment -> depth-3 signature (Chen, basepoint) -> Linear.
// B=256, L=256, CIN=8, C=9, SIG_CH=819, OUT=128.
//
// One block per batch. Sequential Chen recurrence over L=256 segments:
//   s1 += dx
//   s2[i][j] += (s1[i] + 0.5*dx[i]) * dx[j]
//   s3[i][j][k] += F(i,j) * dx[k],  F = s2[i][j] + (0.5*s1[i] + dx[i]/6)*dx[j]
// s3 lives in registers (243 threads x 3 consecutive k each, static indices).
// s1/s2 double-buffered in LDS -> one barrier per step.

#define LSEQ 256
#define DXPAD 12

__global__ __launch_bounds__(256) void signet_fwd(
    const float* __restrict__ inp,   // [256, 256, 8]
    const float* __restrict__ W,     // [819, 128]
    const float* __restrict__ bias,  // [128]
    float* __restrict__ out)         // [256, 128]
{
    __shared__ float dxs[LSEQ][DXPAD];   // per-segment increments, 9 used
    __shared__ float s1buf[2][12];
    __shared__ float s2buf[2][84];
    __shared__ float sig[820];
    __shared__ float part[2][128];

    const int tid = threadIdx.x;
    const int b   = blockIdx.x;

    // ---- build dx table: dx[l][0]=dt, dx[l][1..8]=inp diffs (basepoint=0) ----
    {
        const int l = tid;
        const float* row = inp + (size_t)b * 2048 + (size_t)l * 8;
        float4 c0 = *(const float4*)(row);
        float4 c1 = *(const float4*)(row + 4);
        float4 p0 = make_float4(0.f, 0.f, 0.f, 0.f);
        float4 p1 = p0;
        if (l > 0) {
            p0 = *(const float4*)(row - 8);
            p1 = *(const float4*)(row - 4);
        }
        dxs[l][0] = (l > 0) ? (1.0f / 255.0f) : 0.0f;   // t = linspace(0,1,256)
        dxs[l][1] = c0.x - p0.x;
        dxs[l][2] = c0.y - p0.y;
        dxs[l][3] = c0.z - p0.z;
        dxs[l][4] = c0.w - p0.w;
        dxs[l][5] = c1.x - p1.x;
        dxs[l][6] = c1.y - p1.y;
        dxs[l][7] = c1.z - p1.z;
        dxs[l][8] = c1.w - p1.w;
    }
    if (tid < 9)  s1buf[0][tid] = 0.0f;
    if (tid < 81) s2buf[0][tid] = 0.0f;

    // s3 ownership: thread t<243 owns (i,j, k0..k0+2), p=t/3 -> (i,j), m=t%3
    const bool own3 = (tid < 243);
    const int  pp = tid / 3;          // 0..80  (for own3)
    const int  mm = tid - pp * 3;     // 0..2
    const int  si = pp / 9;
    const int  sj = pp - si * 9;
    const int  sk = 3 * mm;
    const int  i2 = (tid < 81) ? (tid / 9) : 0;
    const int  j2 = (tid < 81) ? (tid - i2 * 9) : 0;

    float acc0 = 0.f, acc1 = 0.f, acc2 = 0.f;

    __syncthreads();

    // ---- Chen scan, one barrier per step (double-buffered s1/s2) ----
    for (int l = 0; l < LSEQ; ++l) {
        const int cur = l & 1;
        const int nxt = cur ^ 1;

        if (own3) {
            const float dxi  = dxs[l][si];
            const float dxj  = dxs[l][sj];
            const float s1i  = s1buf[cur][si];
            const float s2ij = s2buf[cur][pp];
            const float F = fmaf(fmaf(dxi, (1.0f / 6.0f), 0.5f * s1i), dxj, s2ij);
            acc0 = fmaf(F, dxs[l][sk],     acc0);
            acc1 = fmaf(F, dxs[l][sk + 1], acc1);
            acc2 = fmaf(F, dxs[l][sk + 2], acc2);
        }
        if (tid < 81) {
            const float dxi = dxs[l][i2];
            const float dxj = dxs[l][j2];
            s2buf[nxt][tid] = fmaf(fmaf(0.5f, dxi, s1buf[cur][i2]), dxj,
                                   s2buf[cur][tid]);
        }
        if (tid < 9) {
            s1buf[nxt][tid] = s1buf[cur][tid] + dxs[l][tid];
        }
        __syncthreads();
    }
    // after 256 iterations final state is in buffer 0

    // ---- assemble signature vector [s1(9) | s2(81) | s3(729)] ----
    if (tid < 9)  sig[tid]     = s1buf[0][tid];
    if (tid < 81) sig[9 + tid] = s2buf[0][tid];
    if (own3) {
        const int base = 90 + pp * 9 + sk;
        sig[base]     = acc0;
        sig[base + 1] = acc1;
        sig[base + 2] = acc2;
    }
    __syncthreads();

    // ---- linear: y[o] = b[o] + sum_ch sig[ch] * W[ch][o] ----
    const int o    = tid & 127;
    const int half = tid >> 7;
    float acc = 0.f;
    for (int ch = half; ch < 819; ch += 2) {
        acc = fmaf(sig[ch], W[(size_t)ch * 128 + o], acc);
    }
    part[half][o] = acc;
    __syncthreads();
    if (tid < 128) {
        out[(size_t)b * 128 + tid] = part[0][tid] + part[1][tid] + bias[tid];
    }
}

extern "C" void kernel_launch(void* const* d_in, const int* in_sizes, int n_in,
                              void* d_out, int out_size, void* d_ws, size_t ws_size,
                              hipStream_t stream) {
    const float* inp  = (const float*)d_in[0];
    const float* W    = (const float*)d_in[1];
    const float* bias = (const float*)d_in[2];
    float* out = (float*)d_out;
    (void)in_sizes; (void)n_in; (void)out_size; (void)d_ws; (void)ws_size;

    dim3 grid(256), block(256);
    hipLaunchKernelGGL(signet_fwd, grid, block, 0, stream, inp, W, bias, out);
}

// Round 2
// 27.264 us; speedup vs baseline: 3.5176x; 3.5176x over previous
//
#include <hip/hip_runtime.h>

// SigNet forward, closed-form (scan-free) depth-3 signature + Linear.
// B=256, L=256, CIN=8, C=9, SIG_CH=819, OUT=128.
//
// s1[i]       = x_L[i]
// s2[i][j]    = sum_l w_l[i] * d_l[j]                  w = x_{l-1} + 0.5*dx
// s3[i][j][k] = s2[i][j]*x_L[k]
//             + sum_l ( z_l[i]*d_l[j]*d_l[k] - w_l[i]*d_l[j]*x_l[k] )
//                                                      z = 0.5*x_{l-1} + dx/6
// All pure reductions over l -> no barriers in the main loop.

#define PAD 260   // floats per LDS row: %4==0 (float4), %32==4 (bank tiling)

__global__ __launch_bounds__(256) void signet_fwd(
    const float* __restrict__ inp,   // [256, 256, 8]
    const float* __restrict__ W,     // [819, 128]
    const float* __restrict__ bias,  // [128]
    float* __restrict__ out)         // [256, 128]
{
    __shared__ __align__(16) float Wt[9][PAD];
    __shared__ __align__(16) float Zt[9][PAD];
    __shared__ __align__(16) float Dt[9][PAD];
    __shared__ __align__(16) float Xt[9][PAD];
    __shared__ float sig[820];
    __shared__ __align__(16) float4 pbuf[8][32];

    const int tid = threadIdx.x;
    const int b   = blockIdx.x;

    // ---- prep: column t = segment t+1; path point P_s = aug input row s-1 ----
    {
        const int t = tid;
        const float* rc = inp + (size_t)b * 2048 + (size_t)t * 8;
        float cur[9], prv[9];
        cur[0] = (float)t * (1.0f / 255.0f);              // time channel
        float4 c0 = *(const float4*)rc;
        float4 c1 = *(const float4*)(rc + 4);
        cur[1] = c0.x; cur[2] = c0.y; cur[3] = c0.z; cur[4] = c0.w;
        cur[5] = c1.x; cur[6] = c1.y; cur[7] = c1.z; cur[8] = c1.w;
        if (t > 0) {
            prv[0] = (float)(t - 1) * (1.0f / 255.0f);
            float4 p0 = *(const float4*)(rc - 8);
            float4 p1 = *(const float4*)(rc - 4);
            prv[1] = p0.x; prv[2] = p0.y; prv[3] = p0.z; prv[4] = p0.w;
            prv[5] = p1.x; prv[6] = p1.y; prv[7] = p1.z; prv[8] = p1.w;
        } else {
            #pragma unroll
            for (int c = 0; c < 9; ++c) prv[c] = 0.0f;    // basepoint
        }
        #pragma unroll
        for (int c = 0; c < 9; ++c) {
            const float d = cur[c] - prv[c];
            Dt[c][t] = d;
            Xt[c][t] = cur[c];
            Wt[c][t] = prv[c] + 0.5f * d;
            Zt[c][t] = 0.5f * prv[c] + d * (1.0f / 6.0f);
        }
    }
    __syncthreads();

    // ---- main reductions: thread < 243 owns (i, j, k0..k0+2) ----
    const bool own3 = (tid < 243);
    const int  pp = tid / 3;
    const int  mm = tid - pp * 3;
    const int  si = pp / 9;
    const int  sj = pp - si * 9;
    const int  sk = mm * 3;

    float a0 = 0.f, a1 = 0.f, a2 = 0.f, s2a = 0.f;

    if (own3) {
        const float4* w4 = (const float4*)Wt[si];
        const float4* z4 = (const float4*)Zt[si];
        const float4* dj = (const float4*)Dt[sj];
        const float4* x0 = (const float4*)Xt[sk];
        const float4* x1 = (const float4*)Xt[sk + 1];
        const float4* x2 = (const float4*)Xt[sk + 2];
        const float4* d0 = (const float4*)Dt[sk];
        const float4* d1 = (const float4*)Dt[sk + 1];
        const float4* d2 = (const float4*)Dt[sk + 2];

        #pragma unroll 2
        for (int q = 0; q < 64; ++q) {
            const float4 w = w4[q], z = z4[q], dd = dj[q];
            const float4 X0 = x0[q], X1 = x1[q], X2 = x2[q];
            const float4 D0 = d0[q], D1 = d1[q], D2 = d2[q];
            {   const float u = w.x * dd.x, v = z.x * dd.x;  s2a += u;
                a0 = fmaf(v, D0.x, fmaf(-u, X0.x, a0));
                a1 = fmaf(v, D1.x, fmaf(-u, X1.x, a1));
                a2 = fmaf(v, D2.x, fmaf(-u, X2.x, a2)); }
            {   const float u = w.y * dd.y, v = z.y * dd.y;  s2a += u;
                a0 = fmaf(v, D0.y, fmaf(-u, X0.y, a0));
                a1 = fmaf(v, D1.y, fmaf(-u, X1.y, a1));
                a2 = fmaf(v, D2.y, fmaf(-u, X2.y, a2)); }
            {   const float u = w.z * dd.z, v = z.z * dd.z;  s2a += u;
                a0 = fmaf(v, D0.z, fmaf(-u, X0.z, a0));
                a1 = fmaf(v, D1.z, fmaf(-u, X1.z, a1));
                a2 = fmaf(v, D2.z, fmaf(-u, X2.z, a2)); }
            {   const float u = w.w * dd.w, v = z.w * dd.w;  s2a += u;
                a0 = fmaf(v, D0.w, fmaf(-u, X0.w, a0));
                a1 = fmaf(v, D1.w, fmaf(-u, X1.w, a1));
                a2 = fmaf(v, D2.w, fmaf(-u, X2.w, a2)); }
        }

        // + s2[i][j] * x_L[k]
        const float xl0 = Xt[sk][255], xl1 = Xt[sk + 1][255], xl2 = Xt[sk + 2][255];
        a0 = fmaf(s2a, xl0, a0);
        a1 = fmaf(s2a, xl1, a1);
        a2 = fmaf(s2a, xl2, a2);

        const int base = 90 + pp * 9 + sk;
        sig[base]     = a0;
        sig[base + 1] = a1;
        sig[base + 2] = a2;
        if (mm == 0) sig[9 + pp] = s2a;
    }
    if (tid < 9) sig[tid] = Xt[tid][255];
    __syncthreads();

    // ---- linear: out[b][o] = bias[o] + sum_ch sig[ch]*W[ch][o] ----
    {
        const int oq = tid & 31;     // o-quad: outputs 4*oq..4*oq+3
        const int sl = tid >> 5;     // channel slice 0..7
        float4 acc = make_float4(0.f, 0.f, 0.f, 0.f);
        const float4* W4 = (const float4*)W;
        for (int ch = sl; ch < 819; ch += 8) {
            const float s = sig[ch];
            const float4 wv = W4[(size_t)ch * 32 + oq];
            acc.x = fmaf(s, wv.x, acc.x);
            acc.y = fmaf(s, wv.y, acc.y);
            acc.z = fmaf(s, wv.z, acc.z);
            acc.w = fmaf(s, wv.w, acc.w);
        }
        pbuf[sl][oq] = acc;
    }
    __syncthreads();
    if (tid < 32) {
        float4 r = pbuf[0][tid];
        #pragma unroll
        for (int s = 1; s < 8; ++s) {
            const float4 p = pbuf[s][tid];
            r.x += p.x; r.y += p.y; r.z += p.z; r.w += p.w;
        }
        const float4 bv = ((const float4*)bias)[tid];
        r.x += bv.x; r.y += bv.y; r.z += bv.z; r.w += bv.w;
        ((float4*)(out + (size_t)b * 128))[tid] = r;
    }
}

extern "C" void kernel_launch(void* const* d_in, const int* in_sizes, int n_in,
                              void* d_out, int out_size, void* d_ws, size_t ws_size,
                              hipStream_t stream) {
    const float* inp  = (const float*)d_in[0];
    const float* Wp   = (const float*)d_in[1];
    const float* bias = (const float*)d_in[2];
    float* outp = (float*)d_out;
    (void)in_sizes; (void)n_in; (void)out_size; (void)d_ws; (void)ws_size;

    hipLaunchKernelGGL(signet_fwd, dim3(256), dim3(256), 0, stream,
                       inp, Wp, bias, outp);
}

// Round 3
// 19.497 us; speedup vs baseline: 4.9188x; 1.3983x over previous
//
#include <hip/hip_runtime.h>

// SigNet forward, closed-form (scan-free) depth-3 signature + Linear.
// B=256, L=256, CIN=8, C=9, SIG_CH=819, OUT=128.
//
// s1[i]       = x_L[i]
// s2[i][j]    = sum_l w_l[i] * d_l[j]                  w = x_{l-1} + 0.5*dx
// s3[i][j][k] = s2[i][j]*x_L[k]
//             + sum_l ( z_l[i]*d_l[j]*d_l[k] - w_l[i]*d_l[j]*x_l[k] )
//                                                      z = 0.5*x_{l-1} + dx/6
// Pure reductions over l -> split l-range across two thread-halves (8 waves),
// combine partials once. No barriers inside the main loop.

#define PAD 260   // floats per LDS row: %4==0 (float4), %32==4 (bank tiling)

__global__ __launch_bounds__(512) void signet_fwd(
    const float* __restrict__ inp,   // [256, 256, 8]
    const float* __restrict__ W,     // [819, 128]
    const float* __restrict__ bias,  // [128]
    float* __restrict__ out)         // [256, 128]
{
    __shared__ __align__(16) float Wt[9][PAD];
    __shared__ __align__(16) float Zt[9][PAD];
    __shared__ __align__(16) float Dt[9][PAD];
    __shared__ __align__(16) float Xt[9][PAD];
    __shared__ float sig[820];
    __shared__ __align__(16) float4 pbuf[16][32];
    __shared__ __align__(16) float4 part3[244];   // half-1 partials (a0,a1,a2,s2a)

    const int tid = threadIdx.x;
    const int b   = blockIdx.x;

    // ---- prep: column t = segment t+1; channels split across thread halves ----
    {
        const int t = tid & 255;
        const float* rc = inp + (size_t)b * 2048 + (size_t)t * 8;
        if (tid < 256) {
            // channels 0..4 (time + input cols 0..3)
            float4 c0 = *(const float4*)rc;
            float4 p0 = make_float4(0.f, 0.f, 0.f, 0.f);
            float  tp = 0.f;
            if (t > 0) { p0 = *(const float4*)(rc - 8); tp = (float)(t - 1) * (1.0f / 255.0f); }
            float cur[5] = { (float)t * (1.0f / 255.0f), c0.x, c0.y, c0.z, c0.w };
            float prv[5] = { tp, p0.x, p0.y, p0.z, p0.w };
            if (t == 0) cur[0] = 0.0f;
            #pragma unroll
            for (int c = 0; c < 5; ++c) {
                const float d = cur[c] - prv[c];
                Dt[c][t] = d;
                Xt[c][t] = cur[c];
                Wt[c][t] = prv[c] + 0.5f * d;
                Zt[c][t] = 0.5f * prv[c] + d * (1.0f / 6.0f);
            }
        } else {
            // channels 5..8 (input cols 4..7)
            float4 c1 = *(const float4*)(rc + 4);
            float4 p1 = make_float4(0.f, 0.f, 0.f, 0.f);
            if (t > 0) p1 = *(const float4*)(rc - 4);
            float cur[4] = { c1.x, c1.y, c1.z, c1.w };
            float prv[4] = { p1.x, p1.y, p1.z, p1.w };
            #pragma unroll
            for (int c = 0; c < 4; ++c) {
                const float d = cur[c] - prv[c];
                Dt[5 + c][t] = d;
                Xt[5 + c][t] = cur[c];
                Wt[5 + c][t] = prv[c] + 0.5f * d;
                Zt[5 + c][t] = 0.5f * prv[c] + d * (1.0f / 6.0f);
            }
        }
    }
    __syncthreads();

    // ---- main reductions: (i,j,k-triple) per thread, l-range per half ----
    const int  half = tid >> 8;          // 0: q 0..31, 1: q 32..63
    const int  lt   = tid & 255;
    const bool own3 = (lt < 243);
    const int  pp = lt / 3;
    const int  mm = lt - pp * 3;
    const int  si = pp / 9;
    const int  sj = pp - si * 9;
    const int  sk = mm * 3;

    float a0 = 0.f, a1 = 0.f, a2 = 0.f, s2a = 0.f;

    if (own3) {
        const int qb = half * 32;
        const float4* w4 = (const float4*)Wt[si] + qb;
        const float4* z4 = (const float4*)Zt[si] + qb;
        const float4* dj = (const float4*)Dt[sj] + qb;
        const float4* x0 = (const float4*)Xt[sk] + qb;
        const float4* x1 = (const float4*)Xt[sk + 1] + qb;
        const float4* x2 = (const float4*)Xt[sk + 2] + qb;
        const float4* d0 = (const float4*)Dt[sk] + qb;
        const float4* d1 = (const float4*)Dt[sk + 1] + qb;
        const float4* d2 = (const float4*)Dt[sk + 2] + qb;

        #pragma unroll 2
        for (int q = 0; q < 32; ++q) {
            const float4 w = w4[q], z = z4[q], dd = dj[q];
            const float4 X0 = x0[q], X1 = x1[q], X2 = x2[q];
            const float4 D0 = d0[q], D1 = d1[q], D2 = d2[q];
            {   const float u = w.x * dd.x, v = z.x * dd.x;  s2a += u;
                a0 = fmaf(v, D0.x, fmaf(-u, X0.x, a0));
                a1 = fmaf(v, D1.x, fmaf(-u, X1.x, a1));
                a2 = fmaf(v, D2.x, fmaf(-u, X2.x, a2)); }
            {   const float u = w.y * dd.y, v = z.y * dd.y;  s2a += u;
                a0 = fmaf(v, D0.y, fmaf(-u, X0.y, a0));
                a1 = fmaf(v, D1.y, fmaf(-u, X1.y, a1));
                a2 = fmaf(v, D2.y, fmaf(-u, X2.y, a2)); }
            {   const float u = w.z * dd.z, v = z.z * dd.z;  s2a += u;
                a0 = fmaf(v, D0.z, fmaf(-u, X0.z, a0));
                a1 = fmaf(v, D1.z, fmaf(-u, X1.z, a1));
                a2 = fmaf(v, D2.z, fmaf(-u, X2.z, a2)); }
            {   const float u = w.w * dd.w, v = z.w * dd.w;  s2a += u;
                a0 = fmaf(v, D0.w, fmaf(-u, X0.w, a0));
                a1 = fmaf(v, D1.w, fmaf(-u, X1.w, a1));
                a2 = fmaf(v, D2.w, fmaf(-u, X2.w, a2)); }
        }
    }

    if (own3 && half) part3[lt] = make_float4(a0, a1, a2, s2a);
    __syncthreads();

    if (own3 && !half) {
        const float4 p = part3[lt];
        a0 += p.x;  a1 += p.y;  a2 += p.z;  s2a += p.w;
        // + s2[i][j] * x_L[k]
        const float xl0 = Xt[sk][255], xl1 = Xt[sk + 1][255], xl2 = Xt[sk + 2][255];
        a0 = fmaf(s2a, xl0, a0);
        a1 = fmaf(s2a, xl1, a1);
        a2 = fmaf(s2a, xl2, a2);
        const int base = 90 + pp * 9 + sk;
        sig[base]     = a0;
        sig[base + 1] = a1;
        sig[base + 2] = a2;
        if (mm == 0) sig[9 + pp] = s2a;
    }
    if (tid < 9) sig[tid] = Xt[tid][255];
    __syncthreads();

    // ---- linear: out[b][o] = bias[o] + sum_ch sig[ch]*W[ch][o] ----
    {
        const int oq = tid & 31;     // outputs 4*oq..4*oq+3
        const int sl = tid >> 5;     // channel slice 0..15
        float4 acc = make_float4(0.f, 0.f, 0.f, 0.f);
        const float4* W4 = (const float4*)W;
        for (int ch = sl; ch < 819; ch += 16) {
            const float s = sig[ch];
            const float4 wv = W4[(size_t)ch * 32 + oq];
            acc.x = fmaf(s, wv.x, acc.x);
            acc.y = fmaf(s, wv.y, acc.y);
            acc.z = fmaf(s, wv.z, acc.z);
            acc.w = fmaf(s, wv.w, acc.w);
        }
        pbuf[sl][oq] = acc;
    }
    __syncthreads();
    if (tid < 32) {
        float4 r = pbuf[0][tid];
        #pragma unroll
        for (int s = 1; s < 16; ++s) {
            const float4 p = pbuf[s][tid];
            r.x += p.x; r.y += p.y; r.z += p.z; r.w += p.w;
        }
        const float4 bv = ((const float4*)bias)[tid];
        r.x += bv.x; r.y += bv.y; r.z += bv.z; r.w += bv.w;
        ((float4*)(out + (size_t)b * 128))[tid] = r;
    }
}

extern "C" void kernel_launch(void* const* d_in, const int* in_sizes, int n_in,
                              void* d_out, int out_size, void* d_ws, size_t ws_size,
                              hipStream_t stream) {
    const float* inp  = (const float*)d_in[0];
    const float* Wp   = (const float*)d_in[1];
    const float* bias = (const float*)d_in[2];
    float* outp = (float*)d_out;
    (void)in_sizes; (void)n_in; (void)out_size; (void)d_ws; (void)ws_size;

    hipLaunchKernelGGL(signet_fwd, dim3(256), dim3(512), 0, stream,
                       inp, Wp, bias, outp);
}

// Round 4
// 18.246 us; speedup vs baseline: 5.2560x; 1.0686x over previous
//
#include <hip/hip_runtime.h>

// SigNet forward, closed-form (scan-free) depth-3 signature + Linear.
// B=256, L=256, CIN=8, C=9, SIG_CH=819, OUT=128.
//
// s1[i]       = x_L[i]
// s2[i][j]    = sum_l w_l[i] * d_l[j]                   w = x_{l-1} + 0.5*d
// s3[i][j][k] = s2[i][j]*x_L[k]
//             + sum_l ( z_l[i]*d_l[j]*d_l[k] - w_l[i]*d_l[j]*x_l[k] )
//   with z = 0.5*w - d/12,  x = w + 0.5*d  (only W,D tables needed in LDS)
//
// Thread ownership in main loop: (i, ALL j, k-triple) -> 27 threads per
// l-chunk, 16 chunks of 16 columns. 17 ds_read_b128 per float4-of-l per
// thread for 27 (j,k) accumulator pairs. Partials combined via an LDS
// buffer aliased over the dead W/D tables.

#define ROWF   260            // table row stride in floats (260%32==4)
#define NCHUNK 16
#define TPC    27
#define ASTRIDE 29            // per-thread partial stride (odd -> no conflicts)
#define PART_S2_OFF (NCHUNK * TPC * ASTRIDE)          // 12528
#define UNION_FLOATS (PART_S2_OFF + NCHUNK * 81)      // 13824

__global__ __launch_bounds__(512) void signet_fwd(
    const float* __restrict__ inp,   // [256, 256, 8]
    const float* __restrict__ Wg,    // [819, 128]
    const float* __restrict__ bias,  // [128]
    float* __restrict__ out)         // [256, 128]
{
    __shared__ float sig[820];
    __shared__ __align__(16) float u[UNION_FLOATS];

    float* Wt = u;                 // [9][ROWF]  (alive: prep .. xL extract)
    float* Dt = u + 9 * ROWF;      // [9][ROWF]

    const int tid = threadIdx.x;
    const int b   = blockIdx.x;

    // ---- prep: column t = segment t+1 (basepoint 0); channel halves split ----
    {
        const int t = tid & 255;
        const float* rc = inp + (size_t)b * 2048 + (size_t)t * 8;
        if (tid < 256) {
            float4 c0 = *(const float4*)rc;
            float4 p0 = make_float4(0.f, 0.f, 0.f, 0.f);
            float  tp = 0.f;
            if (t > 0) { p0 = *(const float4*)(rc - 8); tp = (float)(t - 1) * (1.0f / 255.0f); }
            float cur[5] = { (float)t * (1.0f / 255.0f), c0.x, c0.y, c0.z, c0.w };
            float prv[5] = { tp, p0.x, p0.y, p0.z, p0.w };
            #pragma unroll
            for (int c = 0; c < 5; ++c) {
                const float d = cur[c] - prv[c];
                Dt[c * ROWF + t] = d;
                Wt[c * ROWF + t] = prv[c] + 0.5f * d;
            }
        } else {
            float4 c1 = *(const float4*)(rc + 4);
            float4 p1 = make_float4(0.f, 0.f, 0.f, 0.f);
            if (t > 0) p1 = *(const float4*)(rc - 4);
            float cur[4] = { c1.x, c1.y, c1.z, c1.w };
            float prv[4] = { p1.x, p1.y, p1.z, p1.w };
            #pragma unroll
            for (int c = 0; c < 4; ++c) {
                const float d = cur[c] - prv[c];
                Dt[(5 + c) * ROWF + t] = d;
                Wt[(5 + c) * ROWF + t] = prv[c] + 0.5f * d;
            }
        }
    }
    __syncthreads();

    // ---- main reductions: chunk = tid/27 handles columns [chunk*16, +16) ----
    const int  chunk = tid / TPC;            // 0..18 (>=16 idle)
    const int  tloc  = tid - chunk * TPC;    // 0..26
    const int  ci    = tloc / 3;             // channel i
    const int  kt    = tloc - ci * 3;        // k-triple: k = 3*kt + m
    const bool act   = (chunk < NCHUNK);

    float a[9][3];
    float s2a[9];
    #pragma unroll
    for (int j = 0; j < 9; ++j) { s2a[j] = 0.f; a[j][0] = 0.f; a[j][1] = 0.f; a[j][2] = 0.f; }

    if (act) {
        const int fb = chunk * 4;                        // float4 column base
        const float4* W4 = (const float4*)u;             // [9][65]
        const float4* D4 = (const float4*)u + 9 * 65;    // [9][65]
        const int k0 = 3 * kt;

        #pragma unroll
        for (int q = 0; q < 4; ++q) {
            const float4 w  = W4[ci * 65 + fb + q];
            const float4 di = D4[ci * 65 + fb + q];
            const float4 Wk0 = W4[(k0 + 0) * 65 + fb + q];
            const float4 Wk1 = W4[(k0 + 1) * 65 + fb + q];
            const float4 Wk2 = W4[(k0 + 2) * 65 + fb + q];
            const float4 Dk0 = D4[(k0 + 0) * 65 + fb + q];
            const float4 Dk1 = D4[(k0 + 1) * 65 + fb + q];
            const float4 Dk2 = D4[(k0 + 2) * 65 + fb + q];

            float4 z, X0, X1, X2;
            z.x = fmaf(-(1.0f / 12.0f), di.x, 0.5f * w.x);
            z.y = fmaf(-(1.0f / 12.0f), di.y, 0.5f * w.y);
            z.z = fmaf(-(1.0f / 12.0f), di.z, 0.5f * w.z);
            z.w = fmaf(-(1.0f / 12.0f), di.w, 0.5f * w.w);
            X0.x = fmaf(0.5f, Dk0.x, Wk0.x); X0.y = fmaf(0.5f, Dk0.y, Wk0.y);
            X0.z = fmaf(0.5f, Dk0.z, Wk0.z); X0.w = fmaf(0.5f, Dk0.w, Wk0.w);
            X1.x = fmaf(0.5f, Dk1.x, Wk1.x); X1.y = fmaf(0.5f, Dk1.y, Wk1.y);
            X1.z = fmaf(0.5f, Dk1.z, Wk1.z); X1.w = fmaf(0.5f, Dk1.w, Wk1.w);
            X2.x = fmaf(0.5f, Dk2.x, Wk2.x); X2.y = fmaf(0.5f, Dk2.y, Wk2.y);
            X2.z = fmaf(0.5f, Dk2.z, Wk2.z); X2.w = fmaf(0.5f, Dk2.w, Wk2.w);

            #pragma unroll
            for (int j = 0; j < 9; ++j) {
                const float4 dj = D4[j * 65 + fb + q];
                { const float uu = w.x * dj.x, vv = z.x * dj.x; s2a[j] += uu;
                  a[j][0] = fmaf(vv, Dk0.x, fmaf(-uu, X0.x, a[j][0]));
                  a[j][1] = fmaf(vv, Dk1.x, fmaf(-uu, X1.x, a[j][1]));
                  a[j][2] = fmaf(vv, Dk2.x, fmaf(-uu, X2.x, a[j][2])); }
                { const float uu = w.y * dj.y, vv = z.y * dj.y; s2a[j] += uu;
                  a[j][0] = fmaf(vv, Dk0.y, fmaf(-uu, X0.y, a[j][0]));
                  a[j][1] = fmaf(vv, Dk1.y, fmaf(-uu, X1.y, a[j][1]));
                  a[j][2] = fmaf(vv, Dk2.y, fmaf(-uu, X2.y, a[j][2])); }
                { const float uu = w.z * dj.z, vv = z.z * dj.z; s2a[j] += uu;
                  a[j][0] = fmaf(vv, Dk0.z, fmaf(-uu, X0.z, a[j][0]));
                  a[j][1] = fmaf(vv, Dk1.z, fmaf(-uu, X1.z, a[j][1]));
                  a[j][2] = fmaf(vv, Dk2.z, fmaf(-uu, X2.z, a[j][2])); }
                { const float uu = w.w * dj.w, vv = z.w * dj.w; s2a[j] += uu;
                  a[j][0] = fmaf(vv, Dk0.w, fmaf(-uu, X0.w, a[j][0]));
                  a[j][1] = fmaf(vv, Dk1.w, fmaf(-uu, X1.w, a[j][1]));
                  a[j][2] = fmaf(vv, Dk2.w, fmaf(-uu, X2.w, a[j][2])); }
            }
        }
    }
    __syncthreads();

    // ---- x_L -> sig[0..8] (tables still alive) ----
    if (tid < 9) {
        const float wl = Wt[tid * ROWF + 255];
        const float dl = Dt[tid * ROWF + 255];
        sig[tid] = fmaf(0.5f, dl, wl);
    }
    __syncthreads();

    // ---- dump partials (aliases over dead tables) ----
    if (act) {
        float* pa = u + (chunk * TPC + tloc) * ASTRIDE;
        #pragma unroll
        for (int j = 0; j < 9; ++j) {
            pa[j * 3 + 0] = a[j][0];
            pa[j * 3 + 1] = a[j][1];
            pa[j * 3 + 2] = a[j][2];
        }
        if (kt == 0) {
            float* ps = u + PART_S2_OFF + chunk * 81 + ci * 9;
            #pragma unroll
            for (int j = 0; j < 9; ++j) ps[j] = s2a[j];
        }
    }
    __syncthreads();

    // ---- combine s2 -> sig[9..89] ----
    if (tid < 81) {
        float s = 0.f;
        #pragma unroll
        for (int c = 0; c < NCHUNK; ++c) s += u[PART_S2_OFF + c * 81 + tid];
        sig[9 + tid] = s;
    }
    __syncthreads();

    // ---- combine s3 -> sig[90..818] ----
    for (int e = tid; e < 729; e += 512) {
        const int i  = e / 81;
        const int r  = e - i * 81;
        const int j  = r / 9;
        const int k  = r - j * 9;
        const int ktv = k / 3;
        const int km  = k - ktv * 3;
        const int toff = (i * 3 + ktv) * ASTRIDE + j * 3 + km;
        float s = 0.f;
        #pragma unroll
        for (int c = 0; c < NCHUNK; ++c) s += u[c * (TPC * ASTRIDE) + toff];
        s = fmaf(sig[9 + i * 9 + j], sig[k], s);
        sig[90 + e] = s;
    }
    __syncthreads();

    // ---- linear: out[b][o] = bias[o] + sum_ch sig[ch]*Wg[ch][o] ----
    {
        const int oq = tid & 31;     // outputs 4*oq..4*oq+3
        const int sl = tid >> 5;     // channel slice 0..15
        float4 acc = make_float4(0.f, 0.f, 0.f, 0.f);
        const float4* Wq = (const float4*)Wg;
        for (int ch = sl; ch < 819; ch += 16) {
            const float s = sig[ch];
            const float4 wv = Wq[(size_t)ch * 32 + oq];
            acc.x = fmaf(s, wv.x, acc.x);
            acc.y = fmaf(s, wv.y, acc.y);
            acc.z = fmaf(s, wv.z, acc.z);
            acc.w = fmaf(s, wv.w, acc.w);
        }
        float4* pbuf = (float4*)u;               // aliases dead partials
        pbuf[sl * 32 + oq] = acc;
    }
    __syncthreads();
    if (tid < 32) {
        const float4* pbuf = (const float4*)u;
        float4 r = pbuf[tid];
        #pragma unroll
        for (int s = 1; s < 16; ++s) {
            const float4 p = pbuf[s * 32 + tid];
            r.x += p.x; r.y += p.y; r.z += p.z; r.w += p.w;
        }
        const float4 bv = ((const float4*)bias)[tid];
        r.x += bv.x; r.y += bv.y; r.z += bv.z; r.w += bv.w;
        ((float4*)(out + (size_t)b * 128))[tid] = r;
    }
}

extern "C" void kernel_launch(void* const* d_in, const int* in_sizes, int n_in,
                              void* d_out, int out_size, void* d_ws, size_t ws_size,
                              hipStream_t stream) {
    const float* inp  = (const float*)d_in[0];
    const float* Wp   = (const float*)d_in[1];
    const float* bias = (const float*)d_in[2];
    float* outp = (float*)d_out;
    (void)in_sizes; (void)n_in; (void)out_size; (void)d_ws; (void)ws_size;

    hipLaunchKernelGGL(signet_fwd, dim3(256), dim3(512), 0, stream,
                       inp, Wp, bias, outp);
}